// Round 14
// baseline (324.684 us; speedup 1.0000x reference)
//
#include <hip/hip_runtime.h>
#include <hip/hip_bf16.h>

#define IN_C 116
#define HEADS 4
#define OUT_C 16
#define OUT_DIM 64
#define NEG_SLOPE 0.2f
#define BN_EPS 1e-5f
#define LIN_BM 32          // nodes per lin3 tile
#define LIN_PAD 36         // padded row (words) for xsT: 16B-aligned float4 reads
#define CAP 32             // slots per node (deg~Poisson(16); P(>32)~1e-4 -> ovf list)
#define OVF_CAP 4096       // overflow side list (exactness safety net)
#define CYCLE 40           // per 40 blocks: 32 fill (8 per partition x 4) + 8 lin3

// ---- prep: INTERLEAVED lin3 (VALU-bound) + dst-partitioned fill (memory-bound).
// Role by blockIdx%5: 4/5 fill, 1/5 lin3. 4 dst-partitions (c = blockIdx&3);
// each partition's fill blocks collectively scan the whole edge list (4x rescan,
// halved from 8x). Correctness does NOT depend on any block->XCD mapping. ----
__global__ __launch_bounds__(256) void prep_kernel(
    const float* __restrict__ x,
    const float* __restrict__ Wl, const float* __restrict__ bl,
    const float* __restrict__ Wr, const float* __restrict__ br,
    const float* __restrict__ Wres, const float* __restrict__ bres,
    float* __restrict__ xl, float* __restrict__ xr, float* __restrict__ xres,
    const int* __restrict__ ei, const float* __restrict__ ea,
    int* __restrict__ cnt, unsigned long long* __restrict__ epack,
    int* __restrict__ ovf, int* __restrict__ ovf_cnt,
    int N, int E, int NBLIN, int FPP, int PART)
{
    __shared__ float xsT[IN_C * LIN_PAD];
    const int b = blockIdx.x;
    const int tid = threadIdx.x;
    const int m = b % CYCLE;

    if (m % 5 == 4) {
        // ---------------- lin3 role ----------------
        const int lb = (b / CYCLE) * 8 + m / 5;
        if (lb >= NBLIN) return;
        const int bn = lb * LIN_BM;

        for (int i = tid; i < LIN_BM * IN_C; i += 256) {
            int n = i / IN_C, k = i - n * IN_C;
            int gn = bn + n;
            xsT[k * LIN_PAD + n] = (gn < N) ? x[(size_t)gn * IN_C + k] : 0.f;
        }
        __syncthreads();

        const int j = tid & 63;       // output channel
        const int t = tid >> 6;       // wave: nodes 8t..8t+7
        const int nbase = 8 * t;

        float al[8] = {0,0,0,0,0,0,0,0};
        float ar[8] = {0,0,0,0,0,0,0,0};
        float as_[8] = {0,0,0,0,0,0,0,0};

        #pragma unroll 4
        for (int k = 0; k < IN_C; ++k) {
            float4 xa = *(const float4*)&xsT[k * LIN_PAD + nbase];
            float4 xb = *(const float4*)&xsT[k * LIN_PAD + nbase + 4];
            float wl  = Wl[k * OUT_DIM + j];
            float wr  = Wr[k * OUT_DIM + j];
            float wsv = Wres[k * OUT_DIM + j];
            float xv[8] = {xa.x, xa.y, xa.z, xa.w, xb.x, xb.y, xb.z, xb.w};
            #pragma unroll
            for (int u = 0; u < 8; ++u) {
                al[u]  += xv[u] * wl;
                ar[u]  += xv[u] * wr;
                as_[u] += xv[u] * wsv;
            }
        }

        float blj = bl[j], brj = br[j], bsj = bres[j];
        #pragma unroll
        for (int u = 0; u < 8; ++u) {
            int gn = bn + nbase + u;
            if (gn < N) {
                xl[(size_t)gn * OUT_DIM + j]   = al[u] + blj;
                xr[(size_t)gn * OUT_DIM + j]   = ar[u] + brj;
                xres[(size_t)gn * OUT_DIM + j] = as_[u] + bsj;
            }
        }
    } else {
        // ---------------- fill role (partition c = b&3) ----------------
        const int c = b & 3;
        // rank among partition c's fill blocks: m = 4k + c, k in 0..9;
        // lin3 slots are k == k0 and k0+5 where k0 = (c+1)%5.
        const int cyc = b / CYCLE;
        const int k   = m >> 2;
        const int k0  = (c + 1) % 5;
        const int q   = k - (k > k0 ? 1 : 0) - (k > k0 + 5 ? 1 : 0);  // 0..7
        const int r   = cyc * 8 + q;                                   // [0, FPP)

        const int lo = c * PART;
        const int hi = (lo + PART < N) ? lo + PART : N;
        const unsigned span = (unsigned)(hi - lo);

        long long e0 = (long long)r * E / FPP;
        long long e1 = (long long)(r + 1) * E / FPP;

#define FILL_ONE(EE, DST)                                                     \
        if ((unsigned)((DST) - lo) < span) {                                  \
            int src = ei[EE];                                                 \
            float av = ea[EE];                                                \
            int slot = atomicAdd(&cnt[DST], 1);                               \
            if (slot < CAP) {                                                 \
                unsigned long long v =                                        \
                    ((unsigned long long)(unsigned)__float_as_uint(av) << 32) \
                    | (unsigned)src;                                          \
                epack[(size_t)(DST) * CAP + slot] = v;                        \
            } else {                                                          \
                int o = atomicAdd(ovf_cnt, 1);                                \
                if (o < OVF_CAP) {                                            \
                    ovf[3 * o] = src; ovf[3 * o + 1] = __float_as_int(av);    \
                    ovf[3 * o + 2] = (DST);                                   \
                }                                                             \
            }                                                                 \
        }

        long long e = e0 + tid;
        // x4 unrolled scan: 4 independent coalesced dst loads in flight
        for (; e + 768 < e1; e += 1024) {
            int d0 = ei[E + e];
            int d1 = ei[E + e + 256];
            int d2 = ei[E + e + 512];
            int d3 = ei[E + e + 768];
            FILL_ONE(e,       d0);
            FILL_ONE(e + 256, d1);
            FILL_ONE(e + 512, d2);
            FILL_ONE(e + 768, d3);
        }
        for (; e < e1; e += 256) {
            int d = ei[E + e];
            FILL_ONE(e, d);
        }
#undef FILL_ONE
    }
}

// ---- gather: full GATv2 per node + FUSED BN channel stats.
// FOUR nodes per wave (16 lanes each, float4 channels per lane). Self-loop
// analytic (src=n, attr=1). Plain softmax (no max shift -- identical math,
// logits O(5)). Unrolled x8. In-place over xr. Stats: shfl-reduce over node
// slots -> LDS over waves -> 64 atomicAdds per block. ----
__global__ __launch_bounds__(256) void gat_gather_kernel(
    const int* __restrict__ cnt, const unsigned long long* __restrict__ epack,
    const int* __restrict__ ovf, const int* __restrict__ ovf_cnt,
    const float* __restrict__ xl, float* __restrict__ xr_hout,
    const float* __restrict__ We, const float* __restrict__ att,
    const float* __restrict__ gat_bias,
    float* __restrict__ chansum, float* __restrict__ chansumsq, int N)
{
    const int lane = threadIdx.x & 63;
    const int wv   = threadIdx.x >> 6;      // wave in block: 0..3
    const int g    = lane >> 4;             // node slot within wave: 0..3
    const int q    = lane & 15;             // channel-quad index (channels 4q..4q+3)
    const int n = blockIdx.x * 16 + wv * 4 + g;
    const bool valid = (n < N);

    float4 o = make_float4(0.f, 0.f, 0.f, 0.f);

    if (valid) {
        const float4 xr4 = *(const float4*)(xr_hout + (size_t)n * OUT_DIM + 4 * q);
        const float4 We4 = *(const float4*)(We + 4 * q);
        const float4 at4 = *(const float4*)(att + 4 * q);

        int len = cnt[n];
        len = len < CAP ? len : CAP;
        const unsigned long long* ep = epack + (size_t)n * CAP;

        // self-loop term: src = n, attr = 1.0
        float den, acc0, acc1, acc2, acc3;
        {
            float4 xv = *(const float4*)(xl + (size_t)n * OUT_DIM + 4 * q);
            float s0 = xv.x + xr4.x + We4.x;
            float s1 = xv.y + xr4.y + We4.y;
            float s2 = xv.z + xr4.z + We4.z;
            float s3 = xv.w + xr4.w + We4.w;
            s0 = s0 > 0.f ? s0 : NEG_SLOPE * s0;
            s1 = s1 > 0.f ? s1 : NEG_SLOPE * s1;
            s2 = s2 > 0.f ? s2 : NEG_SLOPE * s2;
            s3 = s3 > 0.f ? s3 : NEG_SLOPE * s3;
            float pl = at4.x * s0 + at4.y * s1 + at4.z * s2 + at4.w * s3;
            pl += __shfl_xor(pl, 1);
            pl += __shfl_xor(pl, 2);   // 4-lane head reduce
            float ex = __expf(pl);
            den = ex;
            acc0 = ex * xv.x; acc1 = ex * xv.y; acc2 = ex * xv.z; acc3 = ex * xv.w;
        }

#define EDGE_CORE(SRC, AV)                                              \
        {                                                               \
            int src = (SRC);                                            \
            float av = (AV);                                            \
            float4 xv = *(const float4*)(xl + (size_t)src * OUT_DIM + 4*q); \
            float s0 = xv.x + xr4.x + av * We4.x;                       \
            float s1 = xv.y + xr4.y + av * We4.y;                       \
            float s2 = xv.z + xr4.z + av * We4.z;                       \
            float s3 = xv.w + xr4.w + av * We4.w;                       \
            s0 = s0 > 0.f ? s0 : NEG_SLOPE * s0;                        \
            s1 = s1 > 0.f ? s1 : NEG_SLOPE * s1;                        \
            s2 = s2 > 0.f ? s2 : NEG_SLOPE * s2;                        \
            s3 = s3 > 0.f ? s3 : NEG_SLOPE * s3;                        \
            float pl = at4.x * s0 + at4.y * s1 + at4.z * s2 + at4.w * s3; \
            pl += __shfl_xor(pl, 1);                                    \
            pl += __shfl_xor(pl, 2);                                    \
            float ex = __expf(pl);                                      \
            den += ex;                                                  \
            acc0 += ex * xv.x;                                          \
            acc1 += ex * xv.y;                                          \
            acc2 += ex * xv.z;                                          \
            acc3 += ex * xv.w;                                          \
        }

#define EDGE_BODY(PP)                                                   \
        {                                                               \
            unsigned long long v = ep[PP];                              \
            EDGE_CORE((int)(unsigned)(v & 0xffffffffull),               \
                      __uint_as_float((unsigned)(v >> 32)));            \
        }

        int p = 0;
        while (p + 8 <= len) {
            EDGE_BODY(p);     EDGE_BODY(p + 1);
            EDGE_BODY(p + 2); EDGE_BODY(p + 3);
            EDGE_BODY(p + 4); EDGE_BODY(p + 5);
            EDGE_BODY(p + 6); EDGE_BODY(p + 7);
            p += 8;
        }
        while (p + 2 <= len) { EDGE_BODY(p); EDGE_BODY(p + 1); p += 2; }
        if (p < len) EDGE_BODY(p);

        // overflow edges (few): exactness safety net
        int oc = *ovf_cnt;
        if (oc > 0) {
            oc = oc < OVF_CAP ? oc : OVF_CAP;
            for (int ov = 0; ov < oc; ++ov) {
                if (ovf[3 * ov + 2] == n)
                    EDGE_CORE(ovf[3 * ov], __int_as_float(ovf[3 * ov + 1]));
            }
        }
#undef EDGE_BODY
#undef EDGE_CORE

        const float4 bias4 = *(const float4*)(gat_bias + 4 * q);
        float inv = 1.0f / den;
        o.x = acc0 * inv + bias4.x;
        o.y = acc1 * inv + bias4.y;
        o.z = acc2 * inv + bias4.z;
        o.w = acc3 * inv + bias4.w;
        *(float4*)(xr_hout + (size_t)n * OUT_DIM + 4 * q) = o;
    }

    // ---- fused BN stats (all threads participate; invalid contribute 0) ----
    float s0 = o.x, s1 = o.y, s2 = o.z, s3 = o.w;
    float t0 = o.x*o.x, t1 = o.y*o.y, t2 = o.z*o.z, t3 = o.w*o.w;
    // reduce over the 4 node slots (lanes differing in bits 4,5)
    #pragma unroll
    for (int mask = 16; mask <= 32; mask <<= 1) {
        s0 += __shfl_xor(s0, mask); s1 += __shfl_xor(s1, mask);
        s2 += __shfl_xor(s2, mask); s3 += __shfl_xor(s3, mask);
        t0 += __shfl_xor(t0, mask); t1 += __shfl_xor(t1, mask);
        t2 += __shfl_xor(t2, mask); t3 += __shfl_xor(t3, mask);
    }
    __shared__ float sm_s[4][16][4], sm_t[4][16][4];
    if (lane < 16) {
        sm_s[wv][q][0] = s0; sm_s[wv][q][1] = s1;
        sm_s[wv][q][2] = s2; sm_s[wv][q][3] = s3;
        sm_t[wv][q][0] = t0; sm_t[wv][q][1] = t1;
        sm_t[wv][q][2] = t2; sm_t[wv][q][3] = t3;
    }
    __syncthreads();
    if (threadIdx.x < 64) {
        int qq = threadIdx.x >> 2, ii = threadIdx.x & 3;
        float S = sm_s[0][qq][ii] + sm_s[1][qq][ii] + sm_s[2][qq][ii] + sm_s[3][qq][ii];
        float T = sm_t[0][qq][ii] + sm_t[1][qq][ii] + sm_t[2][qq][ii] + sm_t[3][qq][ii];
        atomicAdd(&chansum[threadIdx.x], S);
        atomicAdd(&chansumsq[threadIdx.x], T);
    }
}

// ---- BN (params computed inline from channel sums) + residual + pool.
// batch is SORTED: run-length accumulate, flush one atomic per segment. ----
__global__ __launch_bounds__(256) void bn_res_pool_kernel(
    const float* __restrict__ hraw, const float* __restrict__ xres,
    const float* __restrict__ chansum, const float* __restrict__ chansumsq,
    const float* __restrict__ gamma, const float* __restrict__ beta,
    const int* __restrict__ batch,
    float* __restrict__ pooled, float* __restrict__ cnt, int N)
{
    const int j = threadIdx.x & 63;
    const int t = threadIdx.x >> 6;
    const int base = blockIdx.x * 256;
    const float invN = 1.0f / (float)N;
    const float mj = chansum[j] * invN;
    const float var = chansumsq[j] * invN - mj * mj;
    const float rj = rsqrtf(var + BN_EPS);
    const float gj = gamma[j], bj = beta[j];

    float sum = 0.f, c = 0.f;
    int gcur = -1;
    for (int i = t; i < 256; i += 4) {
        int n = base + i;
        if (n >= N) break;
        int g = batch[n];
        if (g != gcur) {
            if (gcur >= 0) {
                atomicAdd(&pooled[gcur * OUT_DIM + j], sum);
                if (j == 0) atomicAdd(&cnt[gcur], c);
            }
            sum = 0.f; c = 0.f; gcur = g;
        }
        float v = gj * (hraw[(size_t)n * OUT_DIM + j] - mj) * rj + bj
                + xres[(size_t)n * OUT_DIM + j];
        sum += v; c += 1.f;
    }
    if (gcur >= 0) {
        atomicAdd(&pooled[gcur * OUT_DIM + j], sum);
        if (j == 0) atomicAdd(&cnt[gcur], c);
    }
}

// ---- final MLP per graph ----
__global__ __launch_bounds__(64) void mlp_kernel(
    const float* __restrict__ pooled, const float* __restrict__ cnt,
    const float* __restrict__ W1, const float* __restrict__ b1,
    const float* __restrict__ W2, const float* __restrict__ b2,
    float* __restrict__ out, int G)
{
    int g = blockIdx.x, j = threadIdx.x;
    __shared__ float ps[64];
    float c = cnt[g];
    c = c > 1.0f ? c : 1.0f;
    ps[j] = pooled[g * OUT_DIM + j] / c;
    __syncthreads();
    float z = b1[j];
    for (int k = 0; k < 64; ++k) z += ps[k] * W1[k * 64 + j];
    z = z > 0.f ? z : 0.f;
    float o0 = z * W2[j * 2 + 0];
    float o1 = z * W2[j * 2 + 1];
    #pragma unroll
    for (int off = 32; off > 0; off >>= 1) {
        o0 += __shfl_down(o0, off);
        o1 += __shfl_down(o1, off);
    }
    if (j == 0) {
        out[g * 2 + 0] = o0 + b2[0];
        out[g * 2 + 1] = o1 + b2[1];
    }
}

extern "C" void kernel_launch(void* const* d_in, const int* in_sizes, int n_in,
                              void* d_out, int out_size, void* d_ws, size_t ws_size,
                              hipStream_t stream) {
    const float* x        = (const float*)d_in[0];
    const int*   ei       = (const int*)d_in[1];
    const float* ea       = (const float*)d_in[2];
    const int*   batch    = (const int*)d_in[3];
    const float* Wl       = (const float*)d_in[4];
    const float* bl       = (const float*)d_in[5];
    const float* Wr       = (const float*)d_in[6];
    const float* br       = (const float*)d_in[7];
    const float* We       = (const float*)d_in[8];
    const float* att      = (const float*)d_in[9];
    const float* gat_bias = (const float*)d_in[10];
    const float* gamma    = (const float*)d_in[11];
    const float* beta     = (const float*)d_in[12];
    const float* Wres     = (const float*)d_in[13];
    const float* bres     = (const float*)d_in[14];
    const float* W1       = (const float*)d_in[15];
    const float* b1       = (const float*)d_in[16];
    const float* W2       = (const float*)d_in[17];
    const float* b2       = (const float*)d_in[18];
    float* out = (float*)d_out;

    const int N = in_sizes[0] / IN_C;       // 50000
    const int E = in_sizes[1] / 2;          // 800000
    const int G = out_size / 2;             // 100

    // ---- workspace layout ----
    float* ws = (float*)d_ws;
    float* xl      = ws;                                   // N*64
    float* xr      = xl + (size_t)N * OUT_DIM;             // N*64 (becomes hout)
    float* xres    = xr + (size_t)N * OUT_DIM;             // N*64
    unsigned long long* epack =
        (unsigned long long*)(xres + (size_t)N * OUT_DIM); // N*CAP (12.8 MB)
    int*   cnt     = (int*)(epack + (size_t)N * CAP);      // N   <-- zero region start
    int*   ovf_cnt = cnt + N;                              // 1
    float* chansum   = (float*)(ovf_cnt + 1);              // 64
    float* chansumsq = chansum + 64;                       // 64
    float* pooled    = chansumsq + 64;                     // G*64
    float* cntg      = pooled + (size_t)G * OUT_DIM;       // G   <-- zero region end
    int*   ovf       = (int*)(cntg + G);                   // 3*OVF_CAP (not zeroed)

    size_t zero_bytes = (size_t)((char*)(cntg + G) - (char*)cnt);
    hipMemsetAsync(cnt, 0, zero_bytes, stream);

    const int NBLIN = (N + LIN_BM - 1) / LIN_BM;   // 1563
    const int CYC   = (NBLIN + 7) / 8;             // 196 cycles of 40 blocks
    const int T     = CYC * CYCLE;                 // 7840 blocks total
    const int FPP   = CYC * 8;                     // fill blocks per partition (1568)
    const int PART  = (N + 3) / 4;                 // dst range per partition (12500)

    // prep: lin3 (1/5 of blocks) interleaved with 4-partition fill (4/5)
    prep_kernel<<<T, 256, 0, stream>>>(
        x, Wl, bl, Wr, br, Wres, bres, xl, xr, xres,
        ei, ea, cnt, epack, ovf, ovf_cnt, N, E, NBLIN, FPP, PART);

    // GATv2 aggregation + fused BN stats
    gat_gather_kernel<<<(N + 15) / 16, 256, 0, stream>>>(
        cnt, epack, ovf, ovf_cnt, xl, xr, We, att, gat_bias,
        chansum, chansumsq, N);

    // BN + residual + segmented pool (BN params derived inline)
    bn_res_pool_kernel<<<(N + 255) / 256, 256, 0, stream>>>(
        xr, xres, chansum, chansumsq, gamma, beta, batch, pooled, cntg, N);

    // final MLP
    mlp_kernel<<<G, 64, 0, stream>>>(pooled, cntg, W1, b1, W2, b2, out, G);
}

// Round 15
// 272.778 us; speedup vs baseline: 1.1903x; 1.1903x over previous
//
#include <hip/hip_runtime.h>
#include <hip/hip_bf16.h>

#define IN_C 116
#define HEADS 4
#define OUT_C 16
#define OUT_DIM 64
#define NEG_SLOPE 0.2f
#define BN_EPS 1e-5f
#define LIN_BM 32          // nodes per lin3 tile
#define LIN_PAD 36         // padded row (words) for xsT: 16B-aligned float4 reads
#define CAP 32             // slots per node (deg~Poisson(16); P(>32)~1e-4 -> ovf list)
#define OVF_CAP 4096       // overflow side list (exactness safety net)
#define CYCLE 40           // per 40 blocks: 32 fill (8 per partition x 4) + 8 lin3

// ---- prep: INTERLEAVED lin3 (VALU-bound) + dst-partitioned fill (memory-bound).
// Role by blockIdx%5: 4/5 fill, 1/5 lin3. 4 dst-partitions (c = blockIdx&3);
// each partition's fill blocks collectively scan the whole edge list (4x rescan).
// Correctness does NOT depend on any block->XCD mapping. ----
__global__ __launch_bounds__(256) void prep_kernel(
    const float* __restrict__ x,
    const float* __restrict__ Wl, const float* __restrict__ bl,
    const float* __restrict__ Wr, const float* __restrict__ br,
    const float* __restrict__ Wres, const float* __restrict__ bres,
    float* __restrict__ xl, float* __restrict__ xr, float* __restrict__ xres,
    const int* __restrict__ ei, const float* __restrict__ ea,
    int* __restrict__ cnt, unsigned long long* __restrict__ epack,
    int* __restrict__ ovf, int* __restrict__ ovf_cnt,
    int N, int E, int NBLIN, int FPP, int PART)
{
    __shared__ float xsT[IN_C * LIN_PAD];
    const int b = blockIdx.x;
    const int tid = threadIdx.x;
    const int m = b % CYCLE;

    if (m % 5 == 4) {
        // ---------------- lin3 role ----------------
        const int lb = (b / CYCLE) * 8 + m / 5;
        if (lb >= NBLIN) return;
        const int bn = lb * LIN_BM;

        for (int i = tid; i < LIN_BM * IN_C; i += 256) {
            int n = i / IN_C, k = i - n * IN_C;
            int gn = bn + n;
            xsT[k * LIN_PAD + n] = (gn < N) ? x[(size_t)gn * IN_C + k] : 0.f;
        }
        __syncthreads();

        const int j = tid & 63;       // output channel
        const int t = tid >> 6;       // wave: nodes 8t..8t+7
        const int nbase = 8 * t;

        float al[8] = {0,0,0,0,0,0,0,0};
        float ar[8] = {0,0,0,0,0,0,0,0};
        float as_[8] = {0,0,0,0,0,0,0,0};

        #pragma unroll 4
        for (int k = 0; k < IN_C; ++k) {
            float4 xa = *(const float4*)&xsT[k * LIN_PAD + nbase];
            float4 xb = *(const float4*)&xsT[k * LIN_PAD + nbase + 4];
            float wl  = Wl[k * OUT_DIM + j];
            float wr  = Wr[k * OUT_DIM + j];
            float wsv = Wres[k * OUT_DIM + j];
            float xv[8] = {xa.x, xa.y, xa.z, xa.w, xb.x, xb.y, xb.z, xb.w};
            #pragma unroll
            for (int u = 0; u < 8; ++u) {
                al[u]  += xv[u] * wl;
                ar[u]  += xv[u] * wr;
                as_[u] += xv[u] * wsv;
            }
        }

        float blj = bl[j], brj = br[j], bsj = bres[j];
        #pragma unroll
        for (int u = 0; u < 8; ++u) {
            int gn = bn + nbase + u;
            if (gn < N) {
                xl[(size_t)gn * OUT_DIM + j]   = al[u] + blj;
                xr[(size_t)gn * OUT_DIM + j]   = ar[u] + brj;
                xres[(size_t)gn * OUT_DIM + j] = as_[u] + bsj;
            }
        }
    } else {
        // ---------------- fill role (partition c = b&3) ----------------
        const int c = b & 3;
        // rank among partition c's fill blocks: m = 4k + c, k in 0..9;
        // lin3 slots are k == k0 and k0+5 where k0 = (c+1)%5.
        const int cyc = b / CYCLE;
        const int k   = m >> 2;
        const int k0  = (c + 1) % 5;
        const int q   = k - (k > k0 ? 1 : 0) - (k > k0 + 5 ? 1 : 0);  // 0..7
        const int r   = cyc * 8 + q;                                   // [0, FPP)

        const int lo = c * PART;
        const int hi = (lo + PART < N) ? lo + PART : N;
        const unsigned span = (unsigned)(hi - lo);

        long long e0 = (long long)r * E / FPP;
        long long e1 = (long long)(r + 1) * E / FPP;

#define FILL_ONE(EE, DST)                                                     \
        if ((unsigned)((DST) - lo) < span) {                                  \
            int src = ei[EE];                                                 \
            float av = ea[EE];                                                \
            int slot = atomicAdd(&cnt[DST], 1);                               \
            if (slot < CAP) {                                                 \
                unsigned long long v =                                        \
                    ((unsigned long long)(unsigned)__float_as_uint(av) << 32) \
                    | (unsigned)src;                                          \
                epack[(size_t)(DST) * CAP + slot] = v;                        \
            } else {                                                          \
                int o = atomicAdd(ovf_cnt, 1);                                \
                if (o < OVF_CAP) {                                            \
                    ovf[3 * o] = src; ovf[3 * o + 1] = __float_as_int(av);    \
                    ovf[3 * o + 2] = (DST);                                   \
                }                                                             \
            }                                                                 \
        }

        long long e = e0 + tid;
        // x4 unrolled scan: 4 independent coalesced dst loads in flight
        for (; e + 768 < e1; e += 1024) {
            int d0 = ei[E + e];
            int d1 = ei[E + e + 256];
            int d2 = ei[E + e + 512];
            int d3 = ei[E + e + 768];
            FILL_ONE(e,       d0);
            FILL_ONE(e + 256, d1);
            FILL_ONE(e + 512, d2);
            FILL_ONE(e + 768, d3);
        }
        for (; e < e1; e += 256) {
            int d = ei[E + e];
            FILL_ONE(e, d);
        }
#undef FILL_ONE
    }
}

// ---- gather: full GATv2 per node. FOUR nodes per wave (16 lanes each, float4
// channels per lane). Self-loop analytic (src=n, attr=1). Plain softmax (no
// max shift -- identical math, logits O(5)). Unrolled x8. In-place over xr.
// NO fused stats: keep VGPR low + early return -> max occupancy (latency-bound;
// round-14 measured fused stats as -55us via occupancy collapse). ----
__global__ __launch_bounds__(256) void gat_gather_kernel(
    const int* __restrict__ cnt, const unsigned long long* __restrict__ epack,
    const int* __restrict__ ovf, const int* __restrict__ ovf_cnt,
    const float* __restrict__ xl, float* __restrict__ xr_hout,
    const float* __restrict__ We, const float* __restrict__ att,
    const float* __restrict__ gat_bias, int N)
{
    const int lane = threadIdx.x & 63;
    const int wv   = threadIdx.x >> 6;      // wave in block: 0..3
    const int g    = lane >> 4;             // node slot within wave: 0..3
    const int q    = lane & 15;             // channel-quad index (channels 4q..4q+3)
    const int n = blockIdx.x * 16 + wv * 4 + g;
    if (n >= N) return;

    const float4 xr4 = *(const float4*)(xr_hout + (size_t)n * OUT_DIM + 4 * q);
    const float4 We4 = *(const float4*)(We + 4 * q);
    const float4 at4 = *(const float4*)(att + 4 * q);

    int len = cnt[n];
    len = len < CAP ? len : CAP;
    const unsigned long long* ep = epack + (size_t)n * CAP;

    // self-loop term: src = n, attr = 1.0
    float den, acc0, acc1, acc2, acc3;
    {
        float4 xv = *(const float4*)(xl + (size_t)n * OUT_DIM + 4 * q);
        float s0 = xv.x + xr4.x + We4.x;
        float s1 = xv.y + xr4.y + We4.y;
        float s2 = xv.z + xr4.z + We4.z;
        float s3 = xv.w + xr4.w + We4.w;
        s0 = s0 > 0.f ? s0 : NEG_SLOPE * s0;
        s1 = s1 > 0.f ? s1 : NEG_SLOPE * s1;
        s2 = s2 > 0.f ? s2 : NEG_SLOPE * s2;
        s3 = s3 > 0.f ? s3 : NEG_SLOPE * s3;
        float pl = at4.x * s0 + at4.y * s1 + at4.z * s2 + at4.w * s3;
        pl += __shfl_xor(pl, 1);
        pl += __shfl_xor(pl, 2);   // 4-lane head reduce
        float ex = __expf(pl);
        den = ex;
        acc0 = ex * xv.x; acc1 = ex * xv.y; acc2 = ex * xv.z; acc3 = ex * xv.w;
    }

#define EDGE_CORE(SRC, AV)                                              \
    {                                                                   \
        int src = (SRC);                                                \
        float av = (AV);                                                \
        float4 xv = *(const float4*)(xl + (size_t)src * OUT_DIM + 4*q); \
        float s0 = xv.x + xr4.x + av * We4.x;                           \
        float s1 = xv.y + xr4.y + av * We4.y;                           \
        float s2 = xv.z + xr4.z + av * We4.z;                           \
        float s3 = xv.w + xr4.w + av * We4.w;                           \
        s0 = s0 > 0.f ? s0 : NEG_SLOPE * s0;                            \
        s1 = s1 > 0.f ? s1 : NEG_SLOPE * s1;                            \
        s2 = s2 > 0.f ? s2 : NEG_SLOPE * s2;                            \
        s3 = s3 > 0.f ? s3 : NEG_SLOPE * s3;                            \
        float pl = at4.x * s0 + at4.y * s1 + at4.z * s2 + at4.w * s3;   \
        pl += __shfl_xor(pl, 1);                                        \
        pl += __shfl_xor(pl, 2);                                        \
        float ex = __expf(pl);                                          \
        den += ex;                                                      \
        acc0 += ex * xv.x;                                              \
        acc1 += ex * xv.y;                                              \
        acc2 += ex * xv.z;                                              \
        acc3 += ex * xv.w;                                              \
    }

#define EDGE_BODY(PP)                                                   \
    {                                                                   \
        unsigned long long v = ep[PP];                                  \
        EDGE_CORE((int)(unsigned)(v & 0xffffffffull),                   \
                  __uint_as_float((unsigned)(v >> 32)));                \
    }

    int p = 0;
    while (p + 8 <= len) {
        EDGE_BODY(p);     EDGE_BODY(p + 1);
        EDGE_BODY(p + 2); EDGE_BODY(p + 3);
        EDGE_BODY(p + 4); EDGE_BODY(p + 5);
        EDGE_BODY(p + 6); EDGE_BODY(p + 7);
        p += 8;
    }
    while (p + 2 <= len) { EDGE_BODY(p); EDGE_BODY(p + 1); p += 2; }
    if (p < len) EDGE_BODY(p);

    // overflow edges (few): exactness safety net
    int oc = *ovf_cnt;
    if (oc > 0) {
        oc = oc < OVF_CAP ? oc : OVF_CAP;
        for (int o = 0; o < oc; ++o) {
            if (ovf[3 * o + 2] == n)
                EDGE_CORE(ovf[3 * o], __int_as_float(ovf[3 * o + 1]));
        }
    }
#undef EDGE_BODY
#undef EDGE_CORE

    const float4 bias4 = *(const float4*)(gat_bias + 4 * q);
    float inv = 1.0f / den;
    float4 o;
    o.x = acc0 * inv + bias4.x;
    o.y = acc1 * inv + bias4.y;
    o.z = acc2 * inv + bias4.z;
    o.w = acc3 * inv + bias4.w;
    *(float4*)(xr_hout + (size_t)n * OUT_DIM + 4 * q) = o;
}

// ---- stats: channel sum/sumsq for BN (few blocks -> low atomic pressure) ----
__global__ __launch_bounds__(256) void stats_kernel(
    const float* __restrict__ h, float* __restrict__ chansum,
    float* __restrict__ chansumsq, int N)
{
    const int j = threadIdx.x & 63;
    const int t = threadIdx.x >> 6;
    float s = 0.f, ss = 0.f;
    for (int n = blockIdx.x * 4 + t; n < N; n += gridDim.x * 4) {
        float v = h[(size_t)n * OUT_DIM + j];
        s += v; ss += v * v;
    }
    __shared__ float ls[4][64], lss[4][64];
    ls[t][j] = s; lss[t][j] = ss;
    __syncthreads();
    if (t == 0) {
        atomicAdd(&chansum[j],   ls[0][j] + ls[1][j] + ls[2][j] + ls[3][j]);
        atomicAdd(&chansumsq[j], lss[0][j] + lss[1][j] + lss[2][j] + lss[3][j]);
    }
}

// ---- BN (params computed inline from channel sums) + residual + pool.
// batch is SORTED: run-length accumulate, flush one atomic per segment. ----
__global__ __launch_bounds__(256) void bn_res_pool_kernel(
    const float* __restrict__ hraw, const float* __restrict__ xres,
    const float* __restrict__ chansum, const float* __restrict__ chansumsq,
    const float* __restrict__ gamma, const float* __restrict__ beta,
    const int* __restrict__ batch,
    float* __restrict__ pooled, float* __restrict__ cnt, int N)
{
    const int j = threadIdx.x & 63;
    const int t = threadIdx.x >> 6;
    const int base = blockIdx.x * 256;
    const float invN = 1.0f / (float)N;
    const float mj = chansum[j] * invN;
    const float var = chansumsq[j] * invN - mj * mj;
    const float rj = rsqrtf(var + BN_EPS);
    const float gj = gamma[j], bj = beta[j];

    float sum = 0.f, c = 0.f;
    int gcur = -1;
    for (int i = t; i < 256; i += 4) {
        int n = base + i;
        if (n >= N) break;
        int g = batch[n];
        if (g != gcur) {
            if (gcur >= 0) {
                atomicAdd(&pooled[gcur * OUT_DIM + j], sum);
                if (j == 0) atomicAdd(&cnt[gcur], c);
            }
            sum = 0.f; c = 0.f; gcur = g;
        }
        float v = gj * (hraw[(size_t)n * OUT_DIM + j] - mj) * rj + bj
                + xres[(size_t)n * OUT_DIM + j];
        sum += v; c += 1.f;
    }
    if (gcur >= 0) {
        atomicAdd(&pooled[gcur * OUT_DIM + j], sum);
        if (j == 0) atomicAdd(&cnt[gcur], c);
    }
}

// ---- final MLP per graph ----
__global__ __launch_bounds__(64) void mlp_kernel(
    const float* __restrict__ pooled, const float* __restrict__ cnt,
    const float* __restrict__ W1, const float* __restrict__ b1,
    const float* __restrict__ W2, const float* __restrict__ b2,
    float* __restrict__ out, int G)
{
    int g = blockIdx.x, j = threadIdx.x;
    __shared__ float ps[64];
    float c = cnt[g];
    c = c > 1.0f ? c : 1.0f;
    ps[j] = pooled[g * OUT_DIM + j] / c;
    __syncthreads();
    float z = b1[j];
    for (int k = 0; k < 64; ++k) z += ps[k] * W1[k * 64 + j];
    z = z > 0.f ? z : 0.f;
    float o0 = z * W2[j * 2 + 0];
    float o1 = z * W2[j * 2 + 1];
    #pragma unroll
    for (int off = 32; off > 0; off >>= 1) {
        o0 += __shfl_down(o0, off);
        o1 += __shfl_down(o1, off);
    }
    if (j == 0) {
        out[g * 2 + 0] = o0 + b2[0];
        out[g * 2 + 1] = o1 + b2[1];
    }
}

extern "C" void kernel_launch(void* const* d_in, const int* in_sizes, int n_in,
                              void* d_out, int out_size, void* d_ws, size_t ws_size,
                              hipStream_t stream) {
    const float* x        = (const float*)d_in[0];
    const int*   ei       = (const int*)d_in[1];
    const float* ea       = (const float*)d_in[2];
    const int*   batch    = (const int*)d_in[3];
    const float* Wl       = (const float*)d_in[4];
    const float* bl       = (const float*)d_in[5];
    const float* Wr       = (const float*)d_in[6];
    const float* br       = (const float*)d_in[7];
    const float* We       = (const float*)d_in[8];
    const float* att      = (const float*)d_in[9];
    const float* gat_bias = (const float*)d_in[10];
    const float* gamma    = (const float*)d_in[11];
    const float* beta     = (const float*)d_in[12];
    const float* Wres     = (const float*)d_in[13];
    const float* bres     = (const float*)d_in[14];
    const float* W1       = (const float*)d_in[15];
    const float* b1       = (const float*)d_in[16];
    const float* W2       = (const float*)d_in[17];
    const float* b2       = (const float*)d_in[18];
    float* out = (float*)d_out;

    const int N = in_sizes[0] / IN_C;       // 50000
    const int E = in_sizes[1] / 2;          // 800000
    const int G = out_size / 2;             // 100

    // ---- workspace layout ----
    float* ws = (float*)d_ws;
    float* xl      = ws;                                   // N*64
    float* xr      = xl + (size_t)N * OUT_DIM;             // N*64 (becomes hout)
    float* xres    = xr + (size_t)N * OUT_DIM;             // N*64
    unsigned long long* epack =
        (unsigned long long*)(xres + (size_t)N * OUT_DIM); // N*CAP (12.8 MB)
    int*   cnt     = (int*)(epack + (size_t)N * CAP);      // N   <-- zero region start
    int*   ovf_cnt = cnt + N;                              // 1
    float* chansum   = (float*)(ovf_cnt + 1);              // 64
    float* chansumsq = chansum + 64;                       // 64
    float* pooled    = chansumsq + 64;                     // G*64
    float* cntg      = pooled + (size_t)G * OUT_DIM;       // G   <-- zero region end
    int*   ovf       = (int*)(cntg + G);                   // 3*OVF_CAP (not zeroed)

    size_t zero_bytes = (size_t)((char*)(cntg + G) - (char*)cnt);
    hipMemsetAsync(cnt, 0, zero_bytes, stream);

    const int NBLIN = (N + LIN_BM - 1) / LIN_BM;   // 1563
    const int CYC   = (NBLIN + 7) / 8;             // 196 cycles of 40 blocks
    const int T     = CYC * CYCLE;                 // 7840 blocks total
    const int FPP   = CYC * 8;                     // fill blocks per partition (1568)
    const int PART  = (N + 3) / 4;                 // dst range per partition (12500)

    // prep: lin3 (1/5 of blocks) interleaved with 4-partition fill (4/5)
    prep_kernel<<<T, 256, 0, stream>>>(
        x, Wl, bl, Wr, br, Wres, bres, xl, xr, xres,
        ei, ea, cnt, epack, ovf, ovf_cnt, N, E, NBLIN, FPP, PART);

    // Full GATv2 aggregation, atomic-free, 4 nodes/wave, self-loop analytic
    gat_gather_kernel<<<(N + 15) / 16, 256, 0, stream>>>(
        cnt, epack, ovf, ovf_cnt, xl, xr, We, att, gat_bias, N);

    // BN stats
    stats_kernel<<<256, 256, 0, stream>>>(xr, chansum, chansumsq, N);

    // BN + residual + segmented pool (BN params derived inline)
    bn_res_pool_kernel<<<(N + 255) / 256, 256, 0, stream>>>(
        xr, xres, chansum, chansumsq, gamma, beta, batch, pooled, cntg, N);

    // final MLP
    mlp_kernel<<<G, 64, 0, stream>>>(pooled, cntg, W1, b1, W2, b2, out, G);
}